// Round 1
// baseline (1293.039 us; speedup 1.0000x reference)
//
#include <hip/hip_runtime.h>
#include <hip/hip_bf16.h>

#define BB 1024
#define LL 50
#define HH 256
#define AA 100
#define NN 100000
#define NM1 99999

__device__ __forceinline__ float wave_sum(float v) {
#pragma unroll
  for (int off = 32; off; off >>= 1) v += __shfl_xor(v, off, 64);
  return v;
}
__device__ __forceinline__ float wave_max(float v) {
#pragma unroll
  for (int off = 32; off; off >>= 1) v = fmaxf(v, __shfl_xor(v, off, 64));
  return v;
}

// ---------------------------------------------------------------------------
// Kernel A: one block per session b. Fuses gather, Q/K, affinity, softmax,
// attention pooling, last-item concat, and the final linear layer.
// Outputs: affinity [B,L,L] to d_out tail, final_rep [B,H] fp32 to d_ws.
// LDS ~75 KB (gfx950 allows 160 KB static).
// ---------------------------------------------------------------------------
__global__ __launch_bounds__(256) void session_kernel(
    const int* __restrict__ inputs, const float* __restrict__ masks,
    const float* __restrict__ emb, const float* __restrict__ Qw,
    const float* __restrict__ Kw, const float* __restrict__ lin_w,
    const float* __restrict__ lin_b, float* __restrict__ out_aff,
    float* __restrict__ fr) {
  __shared__ float s_x[LL][HH];                 // 51200 B
  __shared__ __hip_bfloat16 s_q[LL][AA + 4];    // 10400 B  Q[l][a]
  __shared__ __hip_bfloat16 s_kT[AA][LL + 2];   // 10400 B  K^T[a][m]
  __shared__ float s_mask[LL];
  __shared__ int s_idx[LL];
  __shared__ float s_row[LL];
  __shared__ float s_p[LL];
  __shared__ float s_cat[2 * HH];
  __shared__ int s_last;

  const int b = blockIdx.x;
  const int tid = threadIdx.x;

  if (tid < LL) {
    s_idx[tid] = inputs[b * LL + tid];
    s_mask[tid] = masks[b * LL + tid];
  }
  __syncthreads();

  // ---- gather x = emb[inputs[b]] into LDS (float4 coalesced) ----
  for (int u = tid; u < LL * (HH / 4); u += 256) {
    int l = u >> 6, c = u & 63;
    ((float4*)&s_x[l][0])[c] = ((const float4*)(emb + (size_t)s_idx[l] * HH))[c];
  }
  __syncthreads();

  // ---- Q,K: thread owns one output column (a). k-outer, l-inner, acc in regs.
  //      x reads are LDS broadcasts (all lanes same address) -> conflict-free.
  if (tid < 2 * AA) {
    const float* W = (tid < AA) ? (Qw + tid * HH) : (Kw + (tid - AA) * HH);
    float acc[LL];
#pragma unroll
    for (int l = 0; l < LL; ++l) acc[l] = 0.f;
    for (int k0 = 0; k0 < HH; k0 += 8) {
      float4 w0 = *(const float4*)(W + k0);
      float4 w1 = *(const float4*)(W + k0 + 4);
#pragma unroll
      for (int l = 0; l < LL; ++l) {
        float4 x0 = *(const float4*)&s_x[l][k0];
        float4 x1 = *(const float4*)&s_x[l][k0 + 4];
        acc[l] += w0.x * x0.x + w0.y * x0.y + w0.z * x0.z + w0.w * x0.w +
                  w1.x * x1.x + w1.y * x1.y + w1.z * x1.z + w1.w * x1.w;
      }
    }
    if (tid < AA) {
#pragma unroll
      for (int l = 0; l < LL; ++l)
        s_q[l][tid] = __float2bfloat16(1.f / (1.f + expf(-acc[l])));
    } else {
      const int a = tid - AA;
#pragma unroll
      for (int l = 0; l < LL; ++l)
        s_kT[a][l] = __float2bfloat16(1.f / (1.f + expf(-acc[l])));
    }
  }
  __syncthreads();

  // ---- affinity[l][m] = Q[l]·K[m] / 10; write raw (incl. diagonal) to out,
  //      accumulate masked row sums. Wave w handles rows l = w, w+4, ...
  {
    const int wv = tid >> 6;
    const int m = tid & 63;
    for (int l = wv; l < LL; l += 4) {
      float acc = 0.f;
      if (m < LL) {
#pragma unroll 10
        for (int a = 0; a < AA; ++a)
          acc += __bfloat162float(s_q[l][a]) * __bfloat162float(s_kT[a][m]);
      }
      const float aff = acc * 0.1f;  // 1/sqrt(A), A=100
      if (m < LL) out_aff[(size_t)b * (LL * LL) + l * LL + m] = aff;
      const float am = (m < LL && m != l) ? aff * s_mask[m] : 0.f;
      const float tot = wave_sum(am);
      if (m == 0) s_row[l] = tot * s_mask[l];
    }
  }
  __syncthreads();

  // ---- softmax over l (stable, matches jax.nn.softmax), mask, renormalize;
  //      also session length -> last item id. Single wave.
  if (tid < 64) {
    const int l = tid;
    const float mk = (l < LL) ? s_mask[l] : 0.f;
    const float v = (l < LL) ? s_row[l] : -3.4e38f;
    const float mx = wave_max(v);
    const float e = (l < LL) ? expf(v - mx) : 0.f;
    const float s1 = wave_sum(e);
    float p = e / s1 * mk;
    const float s2 = wave_sum(p);
    p /= s2;
    if (l < LL) s_p[l] = p;
    const float cnt = wave_sum(mk);
    if (l == 0) s_last = s_idx[(int)(cnt + 0.5f) - 1];
  }
  __syncthreads();

  // ---- att_final (weighted sum of x) + last_emb -> concat in LDS ----
  {
    const int h = tid;
    float acc = 0.f;
#pragma unroll
    for (int l = 0; l < LL; ++l) acc += s_p[l] * s_x[l][h];
    s_cat[h] = acc;
    s_cat[HH + h] = emb[(size_t)s_last * HH + h];
  }
  __syncthreads();

  // ---- final_rep[h] = lin_b[h] + cat · lin_w[h,:] ----
  {
    const int h = tid;
    float acc = lin_b[h];
    const float4* lw = (const float4*)(lin_w + (size_t)h * (2 * HH));
#pragma unroll 16
    for (int j = 0; j < (2 * HH) / 4; ++j) {
      float4 w = lw[j];
      float4 cv = *(const float4*)&s_cat[j * 4];
      acc += w.x * cv.x + w.y * cv.y + w.z * cv.z + w.w * cv.w;
    }
    fr[(size_t)b * HH + h] = acc;
  }
}

// ---------------------------------------------------------------------------
// Kernel B: scores[m][n] = FR[m,:] · emb[1+n,:]   (M=1024, N=99999, K=256)
// fp32 register-tiled GEMM: BM=BN=128, BK=16, 256 threads, 8x8 micro-tile.
// Col mapping n = tx + 16*j -> coalesced stores, broadcast-friendly Bs reads.
// ---------------------------------------------------------------------------
__global__ __launch_bounds__(256) void scores_kernel(
    const float* __restrict__ fr, const float* __restrict__ emb,
    float* __restrict__ out) {
  __shared__ float As[16][132];
  __shared__ float Bs[16][132];
  const int tid = threadIdx.x;
  const int tx = tid & 15, ty = tid >> 4;
  const int n0 = blockIdx.x * 128;
  const int m0 = blockIdx.y * 128;

  const int f0 = tid, f1 = tid + 256;
  const int rA0 = f0 >> 2, c0 = (f0 & 3) << 2;
  const int rA1 = f1 >> 2, c1 = (f1 & 3) << 2;
  const int rB0 = min(1 + n0 + rA0, NM1);  // clamp: load valid, store guarded
  const int rB1 = min(1 + n0 + rA1, NM1);

  const float* pa0 = fr + (size_t)(m0 + rA0) * HH + c0;
  const float* pa1 = fr + (size_t)(m0 + rA1) * HH + c1;
  const float* pb0 = emb + (size_t)rB0 * HH + c0;
  const float* pb1 = emb + (size_t)rB1 * HH + c1;

  float acc[8][8];
#pragma unroll
  for (int i = 0; i < 8; ++i)
#pragma unroll
    for (int j = 0; j < 8; ++j) acc[i][j] = 0.f;

  for (int k0 = 0; k0 < HH; k0 += 16) {
    const float4 a0 = *(const float4*)(pa0 + k0);
    const float4 a1 = *(const float4*)(pa1 + k0);
    const float4 b0 = *(const float4*)(pb0 + k0);
    const float4 b1 = *(const float4*)(pb1 + k0);
    __syncthreads();
    As[c0 + 0][rA0] = a0.x; As[c0 + 1][rA0] = a0.y;
    As[c0 + 2][rA0] = a0.z; As[c0 + 3][rA0] = a0.w;
    As[c1 + 0][rA1] = a1.x; As[c1 + 1][rA1] = a1.y;
    As[c1 + 2][rA1] = a1.z; As[c1 + 3][rA1] = a1.w;
    Bs[c0 + 0][rA0] = b0.x; Bs[c0 + 1][rA0] = b0.y;
    Bs[c0 + 2][rA0] = b0.z; Bs[c0 + 3][rA0] = b0.w;
    Bs[c1 + 0][rA1] = b1.x; Bs[c1 + 1][rA1] = b1.y;
    Bs[c1 + 2][rA1] = b1.z; Bs[c1 + 3][rA1] = b1.w;
    __syncthreads();
#pragma unroll
    for (int kk = 0; kk < 16; ++kk) {
      float av[8], bv[8];
      *(float4*)&av[0] = *(const float4*)&As[kk][ty * 8];
      *(float4*)&av[4] = *(const float4*)&As[kk][ty * 8 + 4];
#pragma unroll
      for (int j = 0; j < 8; ++j) bv[j] = Bs[kk][tx + 16 * j];
#pragma unroll
      for (int i = 0; i < 8; ++i)
#pragma unroll
        for (int j = 0; j < 8; ++j) acc[i][j] += av[i] * bv[j];
    }
  }

#pragma unroll
  for (int i = 0; i < 8; ++i) {
    const int m = m0 + ty * 8 + i;
    const size_t rowbase = (size_t)m * NM1;
#pragma unroll
    for (int j = 0; j < 8; ++j) {
      const int n = n0 + tx + 16 * j;
      if (n < NM1) out[rowbase + n] = acc[i][j];
    }
  }
}

extern "C" void kernel_launch(void* const* d_in, const int* in_sizes, int n_in,
                              void* d_out, int out_size, void* d_ws,
                              size_t ws_size, hipStream_t stream) {
  const int* inputs = (const int*)d_in[0];
  const float* masks = (const float*)d_in[1];
  const float* emb = (const float*)d_in[2];
  const float* Qw = (const float*)d_in[3];
  const float* Kw = (const float*)d_in[4];
  const float* lin_w = (const float*)d_in[5];
  const float* lin_b = (const float*)d_in[6];

  float* out_scores = (float*)d_out;                       // [B, N-1]
  float* out_aff = out_scores + (size_t)BB * NM1;          // [B, L, L]
  float* fr = (float*)d_ws;                                // [B, H] fp32, 1 MB

  session_kernel<<<dim3(BB), dim3(256), 0, stream>>>(
      inputs, masks, emb, Qw, Kw, lin_w, lin_b, out_aff, fr);

  dim3 gridB((NM1 + 127) / 128, BB / 128);
  scores_kernel<<<gridB, dim3(256), 0, stream>>>(fr, emb, out_scores);
}